// Round 3
// baseline (148.294 us; speedup 1.0000x reference)
//
#include <hip/hip_runtime.h>
#include <float.h>

// VectorQuantizer: x [64,64,32,32] f32, weight [1024,64] f32
// out[n] = weight[argmin_k ||x_n - w_k||^2]
// score = 0.5||w||^2 + (-x).w via split-bf16 MFMA (6-step: lo*lo dropped).
// R17 (resubmit — R2 bench was GPUAcquisitionTimeout, never measured).
// R16 post-mortem: direct-global B at 2 waves/SIMD exposed ~200cy L2
// latency (true reg footprint ~190 incl. acc AGPRs -> 2 waves/SIMD on the
// unified file; OccupancyPercent 14.6, MfmaUtil 16).
//   (1) Wave tile halved to 32 lats x 64 codes: areg[2][4]+acc[2][4]+
//       b1/b2[8] => ~115 regs peak -> 4 waves/SIMD (__launch_bounds__(512,4)).
//   (2) 512-thr blocks (8 waves = 4 lat-quarters x 2 code-halves); grid 512;
//       per-block epilogue identical shape to R14 (32 contributors/latent).
//   (3) redk DROPPED: k reconstructed from embedded vid + contributor id.
//       Raw-bit score ties imply identical vid => k ordered by cid; the
//       ascending strict-< scan is already lex-min (score,k). Any masked
//       tie lands under eps => exact rescue. LDS 39.9KB.
//   (4) Keep: direct-global B (WEg 256KB L2-resident, zero K-loop barriers,
//       waves drift), 6-step product + eps 7e-4+5e-5|B1|, setprio on MFMA,
//       short8 XE writes.
// MFMA floor 12.4us; B L2 traffic ~512MB -> L2 ceiling ~15us.
#define NLAT   65536
#define KCODES 1024
#define DIM    64
#define HW     1024
#define LPB    128
#define CPK    128
#define NCHUNK 8
#define XROW   136          // XE padded row (shorts): 272 B

typedef float f32x4 __attribute__((ext_vector_type(4)));
typedef short short8 __attribute__((ext_vector_type(8)));

static __device__ __forceinline__ unsigned short f2bf(float f) {
    unsigned int u = __float_as_uint(f);
    return (unsigned short)((u + 0x7fffu + ((u >> 16) & 1u)) >> 16);   // RNE
}
static __device__ __forceinline__ float bf2f(unsigned short h) {
    return __uint_as_float(((unsigned int)h) << 16);
}

// ---------------------------------------------------------------------------
// Prep: one WAVE per code (grid 256 x 256 thr). Lane d loads w[k][d]
// (coalesced), shuffle-reduces the norm, writes UNSWIZZLED row:
// shorts [0:64) = hi(d), [64:128) = lo(d).
__global__ __launch_bounds__(256)
void vq_prep(const float* __restrict__ w, unsigned short* __restrict__ WEg,
             float* __restrict__ wn) {
    const int wave = threadIdx.x >> 6, lane = threadIdx.x & 63;
    const int k = blockIdx.x * 4 + wave;
    float v = w[(size_t)k * DIM + lane];
    float s = v * v;
    #pragma unroll
    for (int m = 32; m > 0; m >>= 1) s += __shfl_xor(s, m, 64);
    if (lane == 0) wn[k] = 0.5f * s;
    unsigned short h = f2bf(v);
    unsigned short l = f2bf(v - bf2f(h));
    unsigned short* row = WEg + (size_t)k * 128;
    row[lane]      = h;
    row[64 + lane] = l;
}

// ---------------------------------------------------------------------------
// Main: 512 blocks x 512 thr (8 waves = 4 lat-quarters x 2 code-halves).
// Wave tile 32 lats x 64 codes per 128-code chunk; A-frags pinned in regs;
// B fragments loaded straight from global (L2-hit); inline exact rescue.
__global__ __launch_bounds__(512, 4)
void vq_main(const float* __restrict__ x, const float* __restrict__ w,
             const unsigned short* __restrict__ WEg, const float* __restrict__ wn,
             float* __restrict__ out) {
    __shared__ __align__(16) char smem[39952];
    unsigned short* XE = (unsigned short*)smem;        // [128][136] (phase 0 only)
    float* red  = (float*)smem;                        // [32][129] raw scores (post-K, aliases XE)
    float* hb1  = (float*)(smem + 34816);              // [4][128] quarter-reduced score
    int*   hbk  = (int*)(smem + 36864);                // [4][128] quarter-reduced k
    int*   bfin = (int*)(smem + 38912);                // [128] winner k
    int*   amb  = (int*)(smem + 39424);                // [128] ambiguous lat ids
    int*   ambn = (int*)(smem + 39936);                // count

    const int tid  = threadIdx.x;
    const int wave = tid >> 6, lane = tid & 63;
    const int r16  = lane & 15, quad = lane >> 4;
    const int CH = wave & 1;          // code half (64 of each 128-chunk)
    const int LQ = wave >> 1;         // lat quarter (32 lats)

    const int blk = blockIdx.x;
    const int b   = blk >> 3;
    const int hw0 = (blk & 7) * LPB;

    if (tid == 0) ambn[0] = 0;

    // Phase 0: convert NEGATED x tile -> XE[lat][hi 0..63 | lo 64..127].
    // 512 threads: each does 16 channels of one latent, short8 LDS writes.
    {
        const int lat = tid & 127;
        const int hf  = tid >> 7;     // 0..3
        const float* xb = x + (size_t)b * (DIM * HW) + hw0 + lat;
        #pragma unroll
        for (int g = 0; g < 2; ++g) {
            short8 hv, lv;
            #pragma unroll
            for (int j = 0; j < 8; ++j) {
                int chn = hf * 16 + g * 8 + j;
                float v = -xb[chn * HW];          // negate: score = wn + (-x).w
                unsigned short h = f2bf(v);
                hv[j] = (short)h;
                lv[j] = (short)f2bf(v - bf2f(h));
            }
            *(short8*)&XE[lat * XROW + hf * 16 + g * 8]      = hv;
            *(short8*)&XE[lat * XROW + 64 + hf * 16 + g * 8] = lv;
        }
    }
    __syncthreads();

    // A-frags: span 0=hi d0-31, 1=hi d32-63, 2=lo d0-31, 3=lo d32-63.
    // (red aliases XE but is written only after the post-K barrier, and all
    //  waves finish these reads before entering the barrier-free K-loop.)
    short8 areg[2][4];
    #pragma unroll
    for (int lt = 0; lt < 2; ++lt)
        #pragma unroll
        for (int p = 0; p < 4; ++p)
            areg[lt][p] = *(const short8*)&XE[(LQ * 32 + lt * 16 + r16) * XROW + p * 32 + quad * 8];

    float b1[8], b2[8];
    #pragma unroll
    for (int sl = 0; sl < 8; ++sl) { b1[sl] = FLT_MAX; b2[sl] = FLT_MAX; }

    for (int ch = 0; ch < NCHUNK; ++ch) {
        const int r0 = ch * CPK + CH * 64 + r16;         // code row for ct=0
        const unsigned short* wrow = WEg + (size_t)r0 * 128 + quad * 8;

        float wnv[4];
        #pragma unroll
        for (int ct = 0; ct < 4; ++ct) wnv[ct] = wn[r0 + ct * 16];
        f32x4 acc[2][4];
        #pragma unroll
        for (int lt = 0; lt < 2; ++lt)
            #pragma unroll
            for (int ct = 0; ct < 4; ++ct) {
                acc[lt][ct][0] = wnv[ct]; acc[lt][ct][1] = wnv[ct];
                acc[lt][ct][2] = wnv[ct]; acc[lt][ct][3] = wnv[ct];
            }

        // 6-step split product (lo*lo dropped; covered by rescue eps):
        // single-use W spans (lo) first so their loads issue earliest.
        const int AI[6]  = {0, 1, 0, 2, 1, 3};
        const int WSp[6] = {2, 3, 0, 0, 1, 1};
        short8 bf[4];
        #pragma unroll
        for (int s = 0; s < 6; ++s) {
            if (s == 0 || WSp[s] != WSp[s - 1]) {
                #pragma unroll
                for (int ct = 0; ct < 4; ++ct)
                    bf[ct] = *(const short8*)(wrow + ct * 2048 + WSp[s] * 32);
            }
            __builtin_amdgcn_s_setprio(1);
            #pragma unroll
            for (int lt = 0; lt < 2; ++lt)
                #pragma unroll
                for (int ct = 0; ct < 4; ++ct)
                    acc[lt][ct] = __builtin_amdgcn_mfma_f32_16x16x32_bf16(
                        areg[lt][AI[s]], bf[ct], acc[lt][ct], 0, 0, 0);
            __builtin_amdgcn_s_setprio(0);
        }

        // Fold (3 ops/score): pack vid=(ch<<2)|ct in low 5 mantissa bits;
        // b2 = med3(b1,b2,p) exact top-2 update; b1 = min(b1,p).
        #pragma unroll
        for (int ct = 0; ct < 4; ++ct) {
            const unsigned vid = (unsigned)((ch << 2) | ct);
            #pragma unroll
            for (int lt = 0; lt < 2; ++lt)
                #pragma unroll
                for (int r = 0; r < 4; ++r) {
                    int sl = lt * 4 + r;
                    float p = __uint_as_float(
                        (__float_as_uint(acc[lt][ct][r]) & 0xFFFFFFE0u) | vid);
                    b2[sl] = __builtin_amdgcn_fmed3f(b1[sl], b2[sl], p);
                    b1[sl] = fminf(b1[sl], p);
                }
        }
    }

    // ---- Epilogue phase 1: argmin over 32 contributors per latent ----
    // Raw (vid-embedded) scores stored; raw-bit ties => same vid => k
    // ordered by cid, so ascending strict-< scan is lex-min (score,k).
    __syncthreads();   // all waves past K-loop (and XE reads) -> alias safe
    const int cid = CH * 16 + r16;   // contributor id, 0..31
    int kslot[8];
    #pragma unroll
    for (int lt = 0; lt < 2; ++lt)
        #pragma unroll
        for (int r = 0; r < 4; ++r) {
            int sl = lt * 4 + r;
            unsigned ub = __float_as_uint(b1[sl]);
            int vid = (int)(ub & 31u);
            kslot[sl] = (vid >> 2) * 128 + CH * 64 + (vid & 3) * 16 + r16;
            int lat = LQ * 32 + lt * 16 + quad * 4 + r;
            red[cid * 129 + lat] = b1[sl];           // raw, vid kept
        }
    __syncthreads();
    // 4x-parallel: 512 threads, 8 contributors each
    {
        const int lat = tid & 127, hf = tid >> 7;
        const int c0 = hf * 8;
        float s1 = red[c0 * 129 + lat]; int c1 = c0;
        #pragma unroll 4
        for (int c = 1; c < 8; ++c) {
            float s = red[(c0 + c) * 129 + lat];
            if (s < s1) { s1 = s; c1 = c0 + c; }     // ascending => lex-min
        }
        unsigned ub = __float_as_uint(s1);
        int vid = (int)(ub & 31u);
        hb1[hf * 128 + lat] = s1;
        hbk[hf * 128 + lat] = (vid >> 2) * 128 + (c1 >> 4) * 64 + (vid & 3) * 16 + (c1 & 15);
    }
    __syncthreads();
    float B1 = 0.f;
    if (tid < LPB) {
        float sA = hb1[tid]; int kA = hbk[tid];
        #pragma unroll
        for (int g = 1; g < 4; ++g) {
            float sB = hb1[g * 128 + tid];
            if (sB < sA) { sA = sB; kA = hbk[g * 128 + tid]; }
        }
        B1 = sA; bfin[tid] = kA;
    }
    __syncthreads();
    // Phase 2: global 2nd best = min over (holder-of-winner-k ? b2 : b1)
    #pragma unroll
    for (int lt = 0; lt < 2; ++lt)
        #pragma unroll
        for (int r = 0; r < 4; ++r) {
            int sl = lt * 4 + r;
            int lat = LQ * 32 + lt * 16 + quad * 4 + r;
            red[cid * 129 + lat] = (kslot[sl] == bfin[lat]) ? b2[sl] : b1[sl];
        }
    __syncthreads();
    {
        const int lat = tid & 127, hf = tid >> 7;
        float m = red[(hf * 8) * 129 + lat];
        #pragma unroll 4
        for (int c = 1; c < 8; ++c) m = fminf(m, red[(hf * 8 + c) * 129 + lat]);
        hb1[hf * 128 + lat] = m;
    }
    __syncthreads();
    if (tid < LPB) {
        float f2 = fminf(fminf(hb1[tid], hb1[128 + tid]),
                         fminf(hb1[256 + tid], hb1[384 + tid]));
        // eps: split double-rounding + fp32 accum + vid truncation + dropped
        // lo*lo term: base 7e-4, rel 5e-5.
        float eps = 7.0e-4f + 5.0e-5f * fabsf(B1);
        if (f2 - B1 < eps) {
            int pos = atomicAdd(ambn, 1);
            amb[pos] = tid;
        }
    }
    __syncthreads();

    // ---- Inline exact rescue: one wave per ambiguous latent ----
    {
        const int na = ambn[0];
        for (int e = wave; e < na; e += 8) {
            const int lat = amb[e];
            const float* xp = x + (size_t)b * (DIM * HW) + hw0 + lat;
            float xs[DIM];
            #pragma unroll
            for (int d = 0; d < DIM; ++d) xs[d] = xp[d * HW];  // wave-uniform
            float bb = FLT_MAX; int bi = 0;
            #pragma unroll 2
            for (int c = 0; c < 16; ++c) {
                int k = c * 64 + lane;
                const float4* wr = (const float4*)(w + (size_t)k * DIM);
                float a0 = 0.f, a1 = 0.f, a2 = 0.f, a3 = 0.f;
                #pragma unroll
                for (int j = 0; j < 16; ++j) {
                    float4 v = wr[j];
                    a0 += xs[4 * j]     * v.x;  a1 += xs[4 * j + 1] * v.y;
                    a2 += xs[4 * j + 2] * v.z;  a3 += xs[4 * j + 3] * v.w;
                }
                float s = wn[k] - ((a0 + a1) + (a2 + a3));
                if (s < bb) { bb = s; bi = k; }
            }
            #pragma unroll
            for (int off = 32; off > 0; off >>= 1) {   // lex (score,k) argmin
                float ob = __shfl_down(bb, off);
                int   oi = __shfl_down(bi, off);
                if (ob < bb || (ob == bb && oi < bi)) { bb = ob; bi = oi; }
            }
            if (lane == 0) bfin[lat] = bi;
        }
    }
    __syncthreads();

    // ---- Gather: out[n][:] = w[bfin][:]  (coalesced float4) ----
    float* outp = out + (size_t)blk * (LPB * DIM);
    #pragma unroll
    for (int r = 0; r < 4; ++r) {
        int idx = r * 512 + tid;
        int row = idx >> 4, seg = idx & 15;
        int code = bfin[row];
        *(float4*)&outp[idx * 4] = *(const float4*)&w[(size_t)code * DIM + seg * 4];
    }
}

extern "C" void kernel_launch(void* const* d_in, const int* in_sizes, int n_in,
                              void* d_out, int out_size, void* d_ws, size_t ws_size,
                              hipStream_t stream) {
    const float* x = (const float*)d_in[0];
    const float* w = (const float*)d_in[1];
    float* out = (float*)d_out;
    unsigned short* WEg = (unsigned short*)d_ws;                  // 262144 B (hi|lo rows)
    float* wn = (float*)((char*)d_ws + 262144);                   // 4096 B

    vq_prep<<<KCODES / 4, 256, 0, stream>>>(w, WEg, wn);
    vq_main<<<NLAT / LPB, 512, 0, stream>>>(x, w, WEg, wn, out);
}

// Round 4
// 123.208 us; speedup vs baseline: 1.2036x; 1.2036x over previous
//
#include <hip/hip_runtime.h>
#include <float.h>

// VectorQuantizer: x [64,64,32,32] f32, weight [1024,64] f32
// out[n] = weight[argmin_k ||x_n - w_k||^2]
// score = 0.5||w||^2 + (-x).w via split-bf16 MFMA (6-step: lo*lo dropped).
// R18: fit the register footprint to 3 waves/SIMD.
// R17 post-mortem: __launch_bounds__(512,4) => 128-reg budget vs ~140-150
// demand => K-loop scratch spills (VGPR_Count 64, MfmaUtil 11, 88.8us).
// 512-thr blocks also quantize occupancy to 2-or-4 waves/SIMD only.
//   (1) 256-thr blocks (4 waves), __launch_bounds__(256,3): budget ~170,
//       3 waves/SIMD, 3 blocks/CU (LDS 37.9KB => LDS-fit too).
//   (2) Wave tile 64 lats x 32 codes/chunk: areg[4][4](64) + acc[4][2](32)
//       + b1/b2(32) + bf[2](8) + misc ~ 160 regs — no spill.
//   (3) 16 chunks x 64 codes; vid=(ch<<1)|ct (5 bits); 32 contributors per
//       latent (CH in {0,1} x 16 lanes) — epilogue shape unchanged.
//   (4) Keep: direct-global B (WEg 256KB L2-resident, ZERO K-loop barriers,
//       waves drift), 6-step product + eps 7e-4+5e-5|B1|, setprio on MFMA,
//       short8 XE writes, inline exact rescue.
// Raw-float tie-break is not lex-min across (vid,CH) cells, but any masked
// tie => f2-B1=0 < eps => exact rescue. Correctness unaffected.
// MFMA floor 3.1us; B L2 traffic ~512MB -> ~15us L2 ceiling; HBM ~5us.
#define NLAT   65536
#define KCODES 1024
#define DIM    64
#define HW     1024
#define LPB    128
#define CPK    64
#define NCHUNK 16
#define XROW   136          // XE padded row (shorts): 272 B

typedef float f32x4 __attribute__((ext_vector_type(4)));
typedef short short8 __attribute__((ext_vector_type(8)));

static __device__ __forceinline__ unsigned short f2bf(float f) {
    unsigned int u = __float_as_uint(f);
    return (unsigned short)((u + 0x7fffu + ((u >> 16) & 1u)) >> 16);   // RNE
}
static __device__ __forceinline__ float bf2f(unsigned short h) {
    return __uint_as_float(((unsigned int)h) << 16);
}

// ---------------------------------------------------------------------------
// Prep: one WAVE per code (grid 256 x 256 thr). Lane d loads w[k][d]
// (coalesced), shuffle-reduces the norm, writes UNSWIZZLED row:
// shorts [0:64) = hi(d), [64:128) = lo(d).
__global__ __launch_bounds__(256)
void vq_prep(const float* __restrict__ w, unsigned short* __restrict__ WEg,
             float* __restrict__ wn) {
    const int wave = threadIdx.x >> 6, lane = threadIdx.x & 63;
    const int k = blockIdx.x * 4 + wave;
    float v = w[(size_t)k * DIM + lane];
    float s = v * v;
    #pragma unroll
    for (int m = 32; m > 0; m >>= 1) s += __shfl_xor(s, m, 64);
    if (lane == 0) wn[k] = 0.5f * s;
    unsigned short h = f2bf(v);
    unsigned short l = f2bf(v - bf2f(h));
    unsigned short* row = WEg + (size_t)k * 128;
    row[lane]      = h;
    row[64 + lane] = l;
}

// ---------------------------------------------------------------------------
// Main: 512 blocks x 256 thr (4 waves = 2 lat-halves x 2 code-halves).
// Wave tile 64 lats x 32 codes per 64-code chunk; A-frags pinned in regs;
// B fragments loaded straight from global (L2-hit); inline exact rescue.
__global__ __launch_bounds__(256, 3)
void vq_main(const float* __restrict__ x, const float* __restrict__ w,
             const unsigned short* __restrict__ WEg, const float* __restrict__ wn,
             float* __restrict__ out) {
    __shared__ __align__(16) char smem[37904];
    unsigned short* XE = (unsigned short*)smem;        // [128][136] (phase 0 only)
    float* red  = (float*)smem;                        // [32][129] raw scores (post-K, aliases XE)
    float* hb1  = (float*)(smem + 34816);              // [2][128] half-reduced score
    int*   hbk  = (int*)(smem + 35840);                // [2][128] half-reduced k
    int*   bfin = (int*)(smem + 36864);                // [128] winner k
    int*   amb  = (int*)(smem + 37376);                // [128] ambiguous lat ids
    int*   ambn = (int*)(smem + 37888);                // count

    const int tid  = threadIdx.x;
    const int wave = tid >> 6, lane = tid & 63;
    const int r16  = lane & 15, quad = lane >> 4;
    const int LH = wave & 1;          // latent half (64 lats)
    const int CH = wave >> 1;         // code half within each 64-code chunk

    const int blk = blockIdx.x;
    const int b   = blk >> 3;
    const int hw0 = (blk & 7) * LPB;

    if (tid == 0) ambn[0] = 0;

    // Phase 0: convert NEGATED x tile -> XE[lat][hi 0..63 | lo 64..127].
    {
        const int lat  = tid & 127;
        const int half = tid >> 7;
        const float* xb = x + (size_t)b * (DIM * HW) + hw0 + lat;
        #pragma unroll
        for (int g = 0; g < 4; ++g) {
            short8 hv, lv;
            #pragma unroll
            for (int j = 0; j < 8; ++j) {
                int chn = half * 32 + g * 8 + j;
                float v = -xb[chn * HW];          // negate: score = wn + (-x).w
                unsigned short h = f2bf(v);
                hv[j] = (short)h;
                lv[j] = (short)f2bf(v - bf2f(h));
            }
            *(short8*)&XE[lat * XROW + half * 32 + g * 8]      = hv;
            *(short8*)&XE[lat * XROW + 64 + half * 32 + g * 8] = lv;
        }
    }
    __syncthreads();

    // A-frags: span 0=hi d0-31, 1=hi d32-63, 2=lo d0-31, 3=lo d32-63.
    // (red aliases XE but is first written after the post-K barrier, and
    //  every wave finishes these reads before entering the K-loop.)
    short8 areg[4][4];
    #pragma unroll
    for (int lt = 0; lt < 4; ++lt)
        #pragma unroll
        for (int p = 0; p < 4; ++p)
            areg[lt][p] = *(const short8*)&XE[(LH * 64 + lt * 16 + r16) * XROW + p * 32 + quad * 8];

    float b1[16], b2[16];
    #pragma unroll
    for (int sl = 0; sl < 16; ++sl) { b1[sl] = FLT_MAX; b2[sl] = FLT_MAX; }

    for (int ch = 0; ch < NCHUNK; ++ch) {
        const int r0 = ch * CPK + CH * 32 + r16;         // code row for ct=0
        const unsigned short* wrow = WEg + (size_t)r0 * 128 + quad * 8;

        float wnv[2] = {wn[r0], wn[r0 + 16]};
        f32x4 acc[4][2];
        #pragma unroll
        for (int lt = 0; lt < 4; ++lt)
            #pragma unroll
            for (int ct = 0; ct < 2; ++ct) {
                acc[lt][ct][0] = wnv[ct]; acc[lt][ct][1] = wnv[ct];
                acc[lt][ct][2] = wnv[ct]; acc[lt][ct][3] = wnv[ct];
            }

        // 6-step split product (lo*lo dropped; covered by rescue eps):
        // single-use W spans (lo) first so their loads issue earliest.
        const int AI[6]  = {0, 1, 0, 2, 1, 3};
        const int WSp[6] = {2, 3, 0, 0, 1, 1};
        short8 bf[2];
        #pragma unroll
        for (int s = 0; s < 6; ++s) {
            if (s == 0 || WSp[s] != WSp[s - 1]) {
                bf[0] = *(const short8*)(wrow + WSp[s] * 32);
                bf[1] = *(const short8*)(wrow + 2048 + WSp[s] * 32);
            }
            __builtin_amdgcn_s_setprio(1);
            #pragma unroll
            for (int lt = 0; lt < 4; ++lt)
                #pragma unroll
                for (int ct = 0; ct < 2; ++ct)
                    acc[lt][ct] = __builtin_amdgcn_mfma_f32_16x16x32_bf16(
                        areg[lt][AI[s]], bf[ct], acc[lt][ct], 0, 0, 0);
            __builtin_amdgcn_s_setprio(0);
        }

        // Fold (3 ops/score): pack vid=(ch<<1)|ct in low 5 mantissa bits;
        // b2 = med3(b1,b2,p) exact top-2 update; b1 = min(b1,p).
        #pragma unroll
        for (int ct = 0; ct < 2; ++ct) {
            const unsigned vid = (unsigned)((ch << 1) | ct);
            #pragma unroll
            for (int lt = 0; lt < 4; ++lt)
                #pragma unroll
                for (int r = 0; r < 4; ++r) {
                    int sl = lt * 4 + r;
                    float p = __uint_as_float(
                        (__float_as_uint(acc[lt][ct][r]) & 0xFFFFFFE0u) | vid);
                    b2[sl] = __builtin_amdgcn_fmed3f(b1[sl], b2[sl], p);
                    b1[sl] = fminf(b1[sl], p);
                }
        }
    }

    // ---- Epilogue phase 1: argmin over 32 contributors per latent ----
    // Raw (vid-embedded) scores stored; any masked-score tie lands under
    // eps => exact rescue, so raw-float compare order is safe.
    __syncthreads();   // all waves past K-loop (and XE reads) -> alias safe
    const int cid = CH * 16 + r16;   // contributor id, 0..31
    int kslot[16];
    #pragma unroll
    for (int lt = 0; lt < 4; ++lt)
        #pragma unroll
        for (int r = 0; r < 4; ++r) {
            int sl = lt * 4 + r;
            unsigned ub = __float_as_uint(b1[sl]);
            int vid = (int)(ub & 31u);
            kslot[sl] = (vid >> 1) * 64 + CH * 32 + (vid & 1) * 16 + r16;
            int lat = LH * 64 + lt * 16 + quad * 4 + r;
            red[cid * 129 + lat] = b1[sl];           // raw, vid kept
        }
    __syncthreads();
    // 2x-parallel: 256 threads, 16 contributors each
    {
        const int lat = tid & 127, hf = tid >> 7;
        const int c0 = hf * 16;
        float s1 = red[c0 * 129 + lat]; int c1 = c0;
        #pragma unroll 4
        for (int c = 1; c < 16; ++c) {
            float s = red[(c0 + c) * 129 + lat];
            if (s < s1) { s1 = s; c1 = c0 + c; }
        }
        unsigned ub = __float_as_uint(s1);
        int vid = (int)(ub & 31u);
        hb1[hf * 128 + lat] = s1;
        hbk[hf * 128 + lat] = (vid >> 1) * 64 + (c1 >> 4) * 32 + (vid & 1) * 16 + (c1 & 15);
    }
    __syncthreads();
    float B1 = 0.f;
    if (tid < LPB) {
        float sA = hb1[tid];       int kA = hbk[tid];
        float sB = hb1[128 + tid]; int kB = hbk[128 + tid];
        if (sB < sA) { sA = sB; kA = kB; }
        B1 = sA; bfin[tid] = kA;
    }
    __syncthreads();
    // Phase 2: global 2nd best = min over (holder-of-winner-k ? b2 : b1)
    #pragma unroll
    for (int lt = 0; lt < 4; ++lt)
        #pragma unroll
        for (int r = 0; r < 4; ++r) {
            int sl = lt * 4 + r;
            int lat = LH * 64 + lt * 16 + quad * 4 + r;
            red[cid * 129 + lat] = (kslot[sl] == bfin[lat]) ? b2[sl] : b1[sl];
        }
    __syncthreads();
    {
        const int lat = tid & 127, hf = tid >> 7;
        float m = red[(hf * 16) * 129 + lat];
        #pragma unroll 4
        for (int c = 1; c < 16; ++c) m = fminf(m, red[(hf * 16 + c) * 129 + lat]);
        hb1[hf * 128 + lat] = m;
    }
    __syncthreads();
    if (tid < LPB) {
        float f2 = fminf(hb1[tid], hb1[128 + tid]);
        // eps: split double-rounding + fp32 accum + vid truncation + dropped
        // lo*lo term: base 7e-4, rel 5e-5.
        float eps = 7.0e-4f + 5.0e-5f * fabsf(B1);
        if (f2 - B1 < eps) {
            int pos = atomicAdd(ambn, 1);
            amb[pos] = tid;
        }
    }
    __syncthreads();

    // ---- Inline exact rescue: one wave per ambiguous latent ----
    {
        const int na = ambn[0];
        for (int e = wave; e < na; e += 4) {
            const int lat = amb[e];
            const float* xp = x + (size_t)b * (DIM * HW) + hw0 + lat;
            float xs[DIM];
            #pragma unroll
            for (int d = 0; d < DIM; ++d) xs[d] = xp[d * HW];  // wave-uniform
            float bb = FLT_MAX; int bi = 0;
            #pragma unroll 2
            for (int c = 0; c < 16; ++c) {
                int k = c * 64 + lane;
                const float4* wr = (const float4*)(w + (size_t)k * DIM);
                float a0 = 0.f, a1 = 0.f, a2 = 0.f, a3 = 0.f;
                #pragma unroll
                for (int j = 0; j < 16; ++j) {
                    float4 v = wr[j];
                    a0 += xs[4 * j]     * v.x;  a1 += xs[4 * j + 1] * v.y;
                    a2 += xs[4 * j + 2] * v.z;  a3 += xs[4 * j + 3] * v.w;
                }
                float s = wn[k] - ((a0 + a1) + (a2 + a3));
                if (s < bb) { bb = s; bi = k; }
            }
            #pragma unroll
            for (int off = 32; off > 0; off >>= 1) {   // lex (score,k) argmin
                float ob = __shfl_down(bb, off);
                int   oi = __shfl_down(bi, off);
                if (ob < bb || (ob == bb && oi < bi)) { bb = ob; bi = oi; }
            }
            if (lane == 0) bfin[lat] = bi;
        }
    }
    __syncthreads();

    // ---- Gather: out[n][:] = w[bfin][:]  (coalesced float4) ----
    float* outp = out + (size_t)blk * (LPB * DIM);
    #pragma unroll
    for (int r = 0; r < 8; ++r) {
        int idx = r * 256 + tid;
        int row = idx >> 4, seg = idx & 15;
        int code = bfin[row];
        *(float4*)&outp[idx * 4] = *(const float4*)&w[(size_t)code * DIM + seg * 4];
    }
}

extern "C" void kernel_launch(void* const* d_in, const int* in_sizes, int n_in,
                              void* d_out, int out_size, void* d_ws, size_t ws_size,
                              hipStream_t stream) {
    const float* x = (const float*)d_in[0];
    const float* w = (const float*)d_in[1];
    float* out = (float*)d_out;
    unsigned short* WEg = (unsigned short*)d_ws;                  // 262144 B (hi|lo rows)
    float* wn = (float*)((char*)d_ws + 262144);                   // 4096 B

    vq_prep<<<KCODES / 4, 256, 0, stream>>>(w, WEg, wn);
    vq_main<<<NLAT / LPB, 256, 0, stream>>>(x, w, WEg, wn, out);
}